// Round 1
// baseline (370.326 us; speedup 1.0000x reference)
//
#include <hip/hip_runtime.h>
#include <math.h>

#define L      2048
#define NFFT   4096
#define NF     2049   // rfft bins
#define D      32
#define K      32
#define B      32
#define KU     3
#define CCH    64     // recurrence chunk length
#define NCH    32     // L / CCH
#define FT     4      // frequencies per mix block

typedef float2 cplx;

// ---------------------------------------------------------------- FFT core
// In-LDS 4096-point radix-2 complex FFT (DIT after in-place bit reversal).
// tw[j] = exp(-2*pi*i*j/4096), j in [0,2048).
template<bool INV>
__device__ void fft4096(float2* s, const float2* __restrict__ tw) {
  const int tid = threadIdx.x;
  const int nth = blockDim.x;
  // bit-reversal permutation (in-place pair swaps)
  for (int i = tid; i < NFFT; i += nth) {
    int r = __brev(i) >> 20;           // 12-bit reversal
    if (i < r) { float2 a = s[i]; s[i] = s[r]; s[r] = a; }
  }
  __syncthreads();
  int log2len = 1;
  for (int len = 2; len <= NFFT; len <<= 1, ++log2len) {
    const int half = len >> 1;
    const int tshift = 12 - log2len;
    for (int t = tid; t < NFFT / 2; t += nth) {
      int j  = t & (half - 1);
      int g  = t >> (log2len - 1);
      int i0 = (g << log2len) + j;
      int i1 = i0 + half;
      float2 w = tw[j << tshift];
      if (INV) w.y = -w.y;
      float2 a = s[i0], b0 = s[i1];
      float2 wb = make_float2(b0.x * w.x - b0.y * w.y,
                              b0.x * w.y + b0.y * w.x);
      s[i0] = make_float2(a.x + wb.x, a.y + wb.y);
      s[i1] = make_float2(a.x - wb.x, a.y - wb.y);
    }
    __syncthreads();
  }
}

// ---------------------------------------------------------------- kernels
__global__ void k_init_tw(float2* __restrict__ tw) {
  int j = blockIdx.x * blockDim.x + threadIdx.x;
  if (j < NFFT / 2) {
    double ang = -2.0 * 3.14159265358979323846 * (double)j / (double)NFFT;
    tw[j] = make_float2((float)cos(ang), (float)sin(ang));
  }
}

// FFT of eigenvector column k (zero-padded), scaled by eig_vals^0.25.
// Vf layout: (k, f) float2
__global__ void k_fft_v(const float* __restrict__ eig_vecs,
                        const float* __restrict__ eig_vals,
                        const float2* __restrict__ tw,
                        float2* __restrict__ Vf) {
  __shared__ float2 s[NFFT];
  const int k = blockIdx.x, tid = threadIdx.x;
  for (int t = tid; t < L; t += blockDim.x)
    s[t] = make_float2(eig_vecs[t * K + k], 0.f);
  for (int t = L + tid; t < NFFT; t += blockDim.x)
    s[t] = make_float2(0.f, 0.f);
  __syncthreads();
  fft4096<false>(s, tw);
  const float sc = powf(eig_vals[k], 0.25f);
  for (int f = tid; f < NF; f += blockDim.x) {
    float2 v = s[f];
    Vf[(size_t)k * NF + f] = make_float2(v.x * sc, v.y * sc);
  }
}

// W[f,d,o] = sum_k Vf[k,f] * m_phi[k*32+d, o]   layout (f,d,o) float2
__global__ __launch_bounds__(1024) void k_w(const float2* __restrict__ Vf,
                                            const float* __restrict__ m_phi,
                                            float2* __restrict__ W) {
  __shared__ float2 vl[K];
  const int f = blockIdx.x, tid = threadIdx.x;
  if (tid < K) vl[tid] = Vf[(size_t)tid * NF + f];
  __syncthreads();
  const int d = tid >> 5, o = tid & 31;
  float2 acc = make_float2(0.f, 0.f);
  #pragma unroll
  for (int k = 0; k < K; ++k) {
    float m = m_phi[(k * D + d) * D + o];
    float2 v = vl[k];
    acc.x += v.x * m;
    acc.y += v.y * m;
  }
  W[(size_t)f * D * D + d * D + o] = acc;
}

// Forward FFT of u[b,:,d] (zero-padded). U layout: (b, d, f) float2
__global__ void k_fft_u(const float* __restrict__ u,
                        const float2* __restrict__ tw,
                        float2* __restrict__ U) {
  __shared__ float2 s[NFFT];
  const int bd = blockIdx.x;               // b*32 + d
  const int b = bd >> 5, d = bd & 31;
  const int tid = threadIdx.x;
  const float* up = u + (size_t)b * L * D + d;
  for (int t = tid; t < L; t += blockDim.x)
    s[t] = make_float2(up[(size_t)t * D], 0.f);
  for (int t = L + tid; t < NFFT; t += blockDim.x)
    s[t] = make_float2(0.f, 0.f);
  __syncthreads();
  fft4096<false>(s, tw);
  float2* Up = U + (size_t)bd * NF;
  for (int f = tid; f < NF; f += blockDim.x) Up[f] = s[f];
}

// Q[b,o,f] = sum_d U[b,d,f] * W[f,d,o]
__global__ __launch_bounds__(128) void k_mix(const float2* __restrict__ U,
                                             const float2* __restrict__ W,
                                             float2* __restrict__ Q) {
  __shared__ float2 Wt[FT][D * D + 4];   // padded: stride 1028 float2
  __shared__ float2 Ut[D][FT];
  const int f0 = blockIdx.x * FT;
  const int tid = threadIdx.x;           // 128
  for (int idx = tid; idx < FT * D * D; idx += blockDim.x) {
    int fi = idx >> 10, rest = idx & 1023;
    int f = f0 + fi;
    Wt[fi][rest] = (f < NF) ? W[(size_t)f * D * D + rest] : make_float2(0.f, 0.f);
  }
  const int fi = tid & (FT - 1);
  const int o  = tid >> 2;               // 0..31
  const int f  = f0 + fi;
  for (int b = 0; b < B; ++b) {
    {
      int d = tid >> 2, ff = f0 + (tid & 3);
      Ut[d][tid & 3] = (ff < NF) ? U[((size_t)b * D + d) * NF + ff]
                                 : make_float2(0.f, 0.f);
    }
    __syncthreads();
    float2 acc = make_float2(0.f, 0.f);
    #pragma unroll
    for (int d2 = 0; d2 < D; ++d2) {
      float2 uu = Ut[d2][fi];
      float2 ww = Wt[fi][d2 * D + o];
      acc.x += uu.x * ww.x - uu.y * ww.y;
      acc.y += uu.x * ww.y + uu.y * ww.x;
    }
    if (f < NF) Q[((size_t)b * D + o) * NF + f] = acc;
    __syncthreads();
  }
}

// irfft of Q[b,:,o] -> dT layout (b, o, t)
__global__ void k_ifft(const float2* __restrict__ Q,
                       const float2* __restrict__ tw,
                       float* __restrict__ dT) {
  __shared__ float2 s[NFFT];
  const int bo = blockIdx.x, tid = threadIdx.x;
  const float2* Qp = Q + (size_t)bo * NF;
  for (int f = tid; f < NF; f += blockDim.x) s[f] = Qp[f];
  __syncthreads();
  if (tid == 0) { s[0].y = 0.f; s[L].y = 0.f; }
  for (int f = tid + 1; f < L; f += blockDim.x) {
    float2 v = s[f];
    s[NFFT - f] = make_float2(v.x, -v.y);
  }
  __syncthreads();
  fft4096<true>(s, tw);
  float* dp = dT + (size_t)bo * L;
  const float inv = 1.0f / (float)NFFT;
  for (int t = tid; t < L; t += blockDim.x) dp[t] = s[t].x * inv;
}

// delta[b,t,o] = dT[b,o,t] + sum_{k<=min(t,2)} sum_i m_u[o,i,k]*u[b,t-k,i]
#define TT 64
__global__ __launch_bounds__(256) void k_ar(const float* __restrict__ dT,
                                            const float* __restrict__ u,
                                            const float* __restrict__ m_u,
                                            float* __restrict__ delta) {
  __shared__ float Ds[D][TT + 1];
  __shared__ float Us[TT + 2][D];
  __shared__ float Mt[KU][D][D];      // [k][i][o]
  const int b = blockIdx.y;
  const int t0 = blockIdx.x * TT;
  const int tid = threadIdx.x;
  for (int idx = tid; idx < D * D * KU; idx += blockDim.x) {
    int k = idx % KU, i = (idx / KU) % D, o = idx / (KU * D);
    Mt[k][i][o] = m_u[idx];
  }
  for (int idx = tid; idx < D * TT; idx += blockDim.x) {
    int o = idx >> 6, tt = idx & 63;
    Ds[o][tt] = dT[((size_t)b * D + o) * L + t0 + tt];
  }
  for (int idx = tid; idx < (TT + 2) * D; idx += blockDim.x) {
    int j = idx >> 5, i = idx & 31;
    int t = t0 - 2 + j;
    Us[j][i] = (t >= 0) ? u[((size_t)b * L + t) * D + i] : 0.f;
  }
  __syncthreads();
  const int o = tid & 31, ts = tid >> 5;
  for (int tt = ts; tt < TT; tt += 8) {
    int t = t0 + tt;
    float acc = Ds[o][tt];
    #pragma unroll
    for (int k2 = 0; k2 < KU; ++k2) {
      if (t >= k2) {
        const float* ur = Us[tt + 2 - k2];
        #pragma unroll
        for (int i = 0; i < D; ++i) acc += Mt[k2][i][o] * ur[i];
      }
    }
    delta[((size_t)b * L + t) * D + o] = acc;
  }
}

// Tc = T^64 where T = [[M0, M1], [I, 0]] (6 squarings)
__global__ __launch_bounds__(1024) void k_tc(const float* __restrict__ m_y,
                                             float* __restrict__ Tc) {
  __shared__ float A[64][68];
  __shared__ float Bb[64][68];
  const int tid = threadIdx.x;
  for (int idx = tid; idx < 64 * 64; idx += blockDim.x) {
    int r = idx >> 6, c = idx & 63;
    float v;
    if (r < 32) v = m_y[(r * 2 + (c >> 5)) * D + (c & 31)];
    else        v = (c == r - 32) ? 1.f : 0.f;
    A[r][c] = v;
  }
  __syncthreads();
  const int r = tid >> 4, cg = tid & 15;
  for (int it = 0; it < 6; ++it) {
    float4 acc = make_float4(0.f, 0.f, 0.f, 0.f);
    for (int i = 0; i < 64; ++i) {
      float a = A[r][i];
      float4 v = *(const float4*)&A[i][cg * 4];
      acc.x += a * v.x; acc.y += a * v.y; acc.z += a * v.z; acc.w += a * v.w;
    }
    __syncthreads();
    *(float4*)&Bb[r][cg * 4] = acc;
    __syncthreads();
    *(float4*)&A[r][cg * 4] = *(const float4*)&Bb[r][cg * 4];
    __syncthreads();
  }
  for (int idx = tid; idx < 64 * 64; idx += blockDim.x)
    Tc[idx] = A[idx >> 6][idx & 63];
}

// Phase A: zero-state chunk response; emit shat[b,c] = [y_{C-1}; y_{C-2}]
__global__ void k_scanA(const float* __restrict__ delta,
                        const float* __restrict__ m_y,
                        float* __restrict__ shat) {
  __shared__ float yb[2][D];
  const int b = blockIdx.y, c = blockIdx.x;
  const int lane = threadIdx.x;            // 64 = one wave
  const int o = lane & 31, h = lane >> 5;
  float m0[16], m1[16];
  #pragma unroll
  for (int i = 0; i < 16; ++i) {
    m0[i] = m_y[(o * 2 + 0) * D + h * 16 + i];
    m1[i] = m_y[(o * 2 + 1) * D + h * 16 + i];
  }
  if (lane < D) { yb[0][lane] = 0.f; yb[1][lane] = 0.f; }
  __syncthreads();
  const float* dp = delta + ((size_t)b * L + c * CCH) * D;
  float ylast = 0.f, yprev = 0.f;
  for (int r = 0; r < CCH; ++r) {
    const float* y1 = yb[(r + 1) & 1];
    const float* y2 = yb[r & 1];
    float acc = 0.f;
    #pragma unroll
    for (int i = 0; i < 16; ++i)
      acc += m0[i] * y1[h * 16 + i] + m1[i] * y2[h * 16 + i];
    acc += __shfl_xor(acc, 32);
    float y = acc + dp[r * D + o];
    __syncthreads();
    if (h == 0) yb[r & 1][o] = y;
    __syncthreads();
    yprev = ylast; ylast = y;
  }
  if (h == 0) {
    float* sp = shat + ((size_t)b * NCH + c) * 64;
    sp[o] = ylast;
    sp[32 + o] = yprev;
  }
}

// Phase B: inter-chunk state scan, record incoming state per chunk.
__global__ void k_scanB(const float* __restrict__ Tc,
                        const float* __restrict__ shat,
                        float* __restrict__ sin_) {
  __shared__ float TcT[64][65];
  __shared__ float sb[64];
  const int b = blockIdx.x;
  const int r = threadIdx.x;               // 64
  for (int idx = r; idx < 64 * 64; idx += 64) {
    int rr = idx >> 6, cc = idx & 63;
    TcT[cc][rr] = Tc[idx];
  }
  sb[r] = 0.f;
  __syncthreads();
  for (int c = 0; c < NCH; ++c) {
    sin_[((size_t)b * NCH + c) * 64 + r] = sb[r];
    float acc = 0.f;
    #pragma unroll 8
    for (int i = 0; i < 64; ++i) acc += TcT[i][r] * sb[i];
    acc += shat[((size_t)b * NCH + c) * 64 + r];
    __syncthreads();
    sb[r] = acc;
    __syncthreads();
  }
}

// Phase C: re-run each chunk with true incoming state, write output.
__global__ void k_scanC(const float* __restrict__ delta,
                        const float* __restrict__ m_y,
                        const float* __restrict__ sin_,
                        float* __restrict__ out) {
  __shared__ float yb[2][D];
  const int b = blockIdx.y, c = blockIdx.x;
  const int lane = threadIdx.x;
  const int o = lane & 31, h = lane >> 5;
  float m0[16], m1[16];
  #pragma unroll
  for (int i = 0; i < 16; ++i) {
    m0[i] = m_y[(o * 2 + 0) * D + h * 16 + i];
    m1[i] = m_y[(o * 2 + 1) * D + h * 16 + i];
  }
  const float* sp = sin_ + ((size_t)b * NCH + c) * 64;
  if (lane < 32) yb[1][lane] = sp[lane];        // y_{-1}
  else           yb[0][lane - 32] = sp[lane];   // y_{-2}
  __syncthreads();
  const float* dp = delta + ((size_t)b * L + c * CCH) * D;
  float* op = out + ((size_t)b * L + c * CCH) * D;
  for (int r = 0; r < CCH; ++r) {
    const float* y1 = yb[(r + 1) & 1];
    const float* y2 = yb[r & 1];
    float acc = 0.f;
    #pragma unroll
    for (int i = 0; i < 16; ++i)
      acc += m0[i] * y1[h * 16 + i] + m1[i] * y2[h * 16 + i];
    acc += __shfl_xor(acc, 32);
    float y = acc + dp[r * D + o];
    __syncthreads();
    if (h == 0) { yb[r & 1][o] = y; op[r * D + o] = y; }
    __syncthreads();
  }
}

// ---------------------------------------------------------------- launch
extern "C" void kernel_launch(void* const* d_in, const int* in_sizes, int n_in,
                              void* d_out, int out_size, void* d_ws, size_t ws_size,
                              hipStream_t stream) {
  const float* u        = (const float*)d_in[0];
  const float* eig_vals = (const float*)d_in[1];
  const float* eig_vecs = (const float*)d_in[2];
  const float* m_u      = (const float*)d_in[3];
  const float* m_phi    = (const float*)d_in[4];
  const float* m_y      = (const float*)d_in[5];
  float* out = (float*)d_out;

  char* ws = (char*)d_ws;
  size_t off = 0;
  auto alloc = [&](size_t bytes) -> void* {
    void* p = ws + off;
    off += bytes;
    off = (off + 255) & ~(size_t)255;
    return p;
  };
  float2* tw   = (float2*)alloc((size_t)(NFFT / 2) * sizeof(float2));
  float2* Vf   = (float2*)alloc((size_t)K * NF * sizeof(float2));
  float2* W    = (float2*)alloc((size_t)NF * D * D * sizeof(float2));   // 16.8 MB
  float2* U    = (float2*)alloc((size_t)B * D * NF * sizeof(float2));   // 16.8 MB
  float2* Q    = (float2*)alloc((size_t)B * D * NF * sizeof(float2));   // 16.8 MB
  float*  Tc   = (float*)alloc(64 * 64 * sizeof(float));
  float*  shat = (float*)alloc((size_t)B * NCH * 64 * sizeof(float));
  float*  sinb = (float*)alloc((size_t)B * NCH * 64 * sizeof(float));
  // alias: dT reuses W (dead after k_mix); delta reuses U (dead after k_mix)
  float* dT    = (float*)W;
  float* delta = (float*)U;

  k_init_tw<<<8, 256, 0, stream>>>(tw);
  k_fft_v <<<K, 256, 0, stream>>>(eig_vecs, eig_vals, tw, Vf);
  k_w     <<<NF, 1024, 0, stream>>>(Vf, m_phi, W);
  k_fft_u <<<B * D, 256, 0, stream>>>(u, tw, U);
  k_mix   <<<(NF + FT - 1) / FT, 128, 0, stream>>>(U, W, Q);
  k_ifft  <<<B * D, 256, 0, stream>>>(Q, tw, dT);
  k_ar    <<<dim3(L / TT, B), 256, 0, stream>>>(dT, u, m_u, delta);
  k_tc    <<<1, 1024, 0, stream>>>(m_y, Tc);
  k_scanA <<<dim3(NCH, B), 64, 0, stream>>>(delta, m_y, shat);
  k_scanB <<<B, 64, 0, stream>>>(Tc, shat, sinb);
  k_scanC <<<dim3(NCH, B), 64, 0, stream>>>(delta, m_y, sinb, out);
}

// Round 5
// 307.007 us; speedup vs baseline: 1.2062x; 1.2062x over previous
//
#include <hip/hip_runtime.h>
#include <math.h>

#define L     2048
#define NFFT  4096
#define NH    2049          // half-spectrum bins
#define UST   2052          // row stride (in float2) for half-spectrum rows
#define D     32
#define B     32
#define KU    3
#define CCH   64            // recurrence chunk length
#define NCH   32            // L / CCH

// skewed LDS physical address (pad 1 float per 32)
__device__ __forceinline__ int PHY(int i) { return i + (i >> 5); }
// base-4 digit reversal of a 12-bit index
__device__ __forceinline__ int REV4(int i) {
  int r2 = __brev(i) >> 20;
  return ((r2 & 0x555) << 1) | ((r2 >> 1) & 0x555);
}

// ---------------------------------------------------------------- twiddles
__global__ void k_init_tw(float2* __restrict__ tw) {
  int j = blockIdx.x * blockDim.x + threadIdx.x;
  if (j < NFFT) {
    double ang = -2.0 * 3.14159265358979323846 * (double)j / (double)NFFT;
    tw[j] = make_float2((float)cos(ang), (float)sin(ang));
  }
}

// ---------------------------------------------------------------- FFT cores
// Forward: 6 in-place radix-4 DIF stages. Natural in -> base4-digit-reversed out.
__device__ void dif6(float* sre, float* sim, const float2* __restrict__ tw, int tid) {
  #pragma unroll
  for (int st = 0; st < 6; ++st) {
    const int shift = 10 - 2 * st;       // log2(q), q = 1024 >> 2st
    const int q = 1 << shift;
    const int r = 1 << (2 * st);         // N/(4q)
    #pragma unroll
    for (int h = 0; h < 2; ++h) {
      const int idx = tid + h * 512;
      const int j = idx & (q - 1);
      const int g = idx >> shift;
      const int i0 = (g << (shift + 2)) + j;
      const int p0 = PHY(i0), p1 = PHY(i0 + q), p2 = PHY(i0 + 2 * q), p3 = PHY(i0 + 3 * q);
      float ax = sre[p0], ay = sim[p0], bx = sre[p1], by = sim[p1];
      float cx = sre[p2], cy = sim[p2], dx = sre[p3], dy = sim[p3];
      float t0x = ax + cx, t0y = ay + cy, t1x = ax - cx, t1y = ay - cy;
      float t2x = bx + dx, t2y = by + dy, t3x = bx - dx, t3y = by - dy;
      float2 w1 = tw[j * r];
      float w2x = w1.x * w1.x - w1.y * w1.y, w2y = 2.f * w1.x * w1.y;
      float w3x = w2x * w1.x - w2y * w1.y, w3y = w2x * w1.y + w2y * w1.x;
      sre[p0] = t0x + t2x; sim[p0] = t0y + t2y;
      float u1x = t1x + t3y, u1y = t1y - t3x;              // t1 - i*t3
      sre[p1] = u1x * w1.x - u1y * w1.y; sim[p1] = u1x * w1.y + u1y * w1.x;
      float u2x = t0x - t2x, u2y = t0y - t2y;
      sre[p2] = u2x * w2x - u2y * w2y; sim[p2] = u2x * w2y + u2y * w2x;
      float u3x = t1x - t3y, u3y = t1y + t3x;              // t1 + i*t3
      sre[p3] = u3x * w3x - u3y * w3y; sim[p3] = u3x * w3y + u3y * w3x;
    }
    __syncthreads();
  }
}

// Inverse: 6 in-place radix-4 DIT stages (transpose of DIF with conj twiddles).
// base4-digit-reversed in -> natural out. No 1/N scaling here.
__device__ void dit6(float* sre, float* sim, const float2* __restrict__ tw, int tid) {
  #pragma unroll
  for (int st = 0; st < 6; ++st) {
    const int shift = 2 * st;            // log2(q), q = 1<<2st
    const int q = 1 << shift;
    const int r = 1 << (10 - 2 * st);
    #pragma unroll
    for (int h = 0; h < 2; ++h) {
      const int idx = tid + h * 512;
      const int j = idx & (q - 1);
      const int g = idx >> shift;
      const int i0 = (g << (shift + 2)) + j;
      const int p0 = PHY(i0), p1 = PHY(i0 + q), p2 = PHY(i0 + 2 * q), p3 = PHY(i0 + 3 * q);
      float ax = sre[p0], ay = sim[p0], bx = sre[p1], by = sim[p1];
      float cx = sre[p2], cy = sim[p2], dx = sre[p3], dy = sim[p3];
      float2 w1 = tw[j * r]; w1.y = -w1.y;                 // conj
      float w2x = w1.x * w1.x - w1.y * w1.y, w2y = 2.f * w1.x * w1.y;
      float w3x = w2x * w1.x - w2y * w1.y, w3y = w2x * w1.y + w2y * w1.x;
      float bpx = bx * w1.x - by * w1.y, bpy = bx * w1.y + by * w1.x;
      float cpx = cx * w2x - cy * w2y,   cpy = cx * w2y + cy * w2x;
      float dpx = dx * w3x - dy * w3y,   dpy = dx * w3y + dy * w3x;
      float t0x = ax + cpx, t0y = ay + cpy, t1x = ax - cpx, t1y = ay - cpy;
      float t2x = bpx + dpx, t2y = bpy + dpy, t3x = bpx - dpx, t3y = bpy - dpy;
      sre[p0] = t0x + t2x; sim[p0] = t0y + t2y;
      sre[p1] = t1x - t3y; sim[p1] = t1y + t3x;            // t1 + i*t3
      sre[p2] = t0x - t2x; sim[p2] = t0y - t2y;
      sre[p3] = t1x + t3y; sim[p3] = t1y - t3x;            // t1 - i*t3
    }
    __syncthreads();
  }
}

// ---------------------------------------------------------------- transpose u
// u (b, t, d) -> uTp rows (b*16+p) of float2 { u[t][2p], u[t][2p+1] }, t-major.
__global__ __launch_bounds__(256) void k_tr(const float* __restrict__ u,
                                            float2* __restrict__ uTp) {
  __shared__ float tile[64][33];
  const int b = blockIdx.y;
  const int t0 = blockIdx.x * 64;
  const int tid = threadIdx.x;
  for (int i = tid; i < 64 * 32; i += 256) {
    int tl = i >> 5, d = i & 31;
    tile[tl][d] = u[((size_t)b * L + t0 + tl) * D + d];
  }
  __syncthreads();
  for (int i = tid; i < 16 * 64; i += 256) {
    int p = i >> 6, tt = i & 63;
    uTp[((size_t)b * 16 + p) * L + t0 + tt] =
        make_float2(tile[tt][2 * p], tile[tt][2 * p + 1]);
  }
}

// ---------------------------------------------------------------- forward FFT
// blocks 0..511: u-pack (b,p): FFT of z = u[:,2p] + i*u[:,2p+1], unpack ->
//   Ubuf rows (b*32+2p), (b*32+2p+1), half-spectrum f<=2048.
// blocks 512..527: eigvec pack p2: unpack + eigval^0.25 scale -> Vf rows.
__global__ __launch_bounds__(512) void k_fft_fwd(const float2* __restrict__ uTp,
                                                 const float* __restrict__ eig_vecs,
                                                 const float* __restrict__ eig_vals,
                                                 const float2* __restrict__ tw,
                                                 float2* __restrict__ Ubuf,
                                                 float2* __restrict__ Vf) {
  __shared__ float sre[4224];
  __shared__ float sim[4224];
  const int blk = blockIdx.x;
  const int tid = threadIdx.x;
  if (blk < 512) {
    const float2* zp = uTp + (size_t)blk * L;
    for (int t = tid; t < L; t += 512) {
      float2 z = zp[t];
      int p = PHY(t);
      sre[p] = z.x; sim[p] = z.y;
    }
  } else {
    const int p2 = blk - 512;
    for (int t = tid; t < L; t += 512) {
      int p = PHY(t);
      sre[p] = eig_vecs[(size_t)t * D + 2 * p2];
      sim[p] = eig_vecs[(size_t)t * D + 2 * p2 + 1];
    }
  }
  for (int t = L + tid; t < NFFT; t += 512) {
    int p = PHY(t);
    sre[p] = 0.f; sim[p] = 0.f;
  }
  __syncthreads();
  dif6(sre, sim, tw, tid);
  // unpack: U_even = (A + conj(Ac))/2 ; U_odd = -i*(A - conj(Ac))/2
  if (blk < 512) {
    float2* r0 = Ubuf + (size_t)(2 * blk) * UST;       // row (b*32 + 2p)
    float2* r1 = r0 + UST;
    for (int f = tid; f <= 2048; f += 512) {
      int pa = PHY(REV4(f));
      int pc = PHY(REV4((NFFT - f) & (NFFT - 1)));
      float Ax = sre[pa], Ay = sim[pa];
      float Bx = sre[pc], By = -sim[pc];
      r0[f] = make_float2(0.5f * (Ax + Bx), 0.5f * (Ay + By));
      float Dx = Ax - Bx, Dy = Ay - By;
      r1[f] = make_float2(0.5f * Dy, -0.5f * Dx);
    }
  } else {
    const int p2 = blk - 512;
    const float sc0 = powf(eig_vals[2 * p2], 0.25f);
    const float sc1 = powf(eig_vals[2 * p2 + 1], 0.25f);
    float2* r0 = Vf + (size_t)(2 * p2) * UST;
    float2* r1 = r0 + UST;
    for (int f = tid; f <= 2048; f += 512) {
      int pa = PHY(REV4(f));
      int pc = PHY(REV4((NFFT - f) & (NFFT - 1)));
      float Ax = sre[pa], Ay = sim[pa];
      float Bx = sre[pc], By = -sim[pc];
      r0[f] = make_float2(0.5f * sc0 * (Ax + Bx), 0.5f * sc0 * (Ay + By));
      float Dx = Ax - Bx, Dy = Ay - By;
      r1[f] = make_float2(0.5f * sc1 * Dy, -0.5f * sc1 * Dx);
    }
  }
}

// ---------------------------------------------------------------- W build
// Wm[f,d,o] = sum_k Vf[k][f] * m_phi[k*32+d, o]
__global__ __launch_bounds__(1024) void k_w(const float2* __restrict__ Vf,
                                            const float* __restrict__ m_phi,
                                            float2* __restrict__ Wm) {
  __shared__ float2 vl[D];
  const int f = blockIdx.x, tid = threadIdx.x;
  if (tid < D) vl[tid] = Vf[(size_t)tid * UST + f];
  __syncthreads();
  const int d = tid >> 5, o = tid & 31;
  float2 acc = make_float2(0.f, 0.f);
  #pragma unroll
  for (int k = 0; k < D; ++k) {
    float m = m_phi[(k * D + d) * D + o];
    float2 v = vl[k];
    acc.x += v.x * m;
    acc.y += v.y * m;
  }
  Wm[(size_t)f * D * D + d * D + o] = acc;
}

// ---------------------------------------------------------------- mix
// Q[b,o,f] = sum_d Ubuf[b,d,f] * Wm[f,d,o], half-spectrum only.
#define FT 4
__global__ __launch_bounds__(128) void k_mix(const float2* __restrict__ Ubuf,
                                             const float2* __restrict__ Wm,
                                             float2* __restrict__ Qbuf) {
  __shared__ float2 Wl[FT][D * D];
  __shared__ float2 Ul[D][FT];
  const int f0 = blockIdx.x * FT;
  const int tid = threadIdx.x;        // 128 = 4 fi x 32 o
  for (int idx = tid; idx < FT * D * D; idx += 128) {
    int fi = idx >> 10, rest = idx & 1023;
    int f = f0 + fi;
    Wl[fi][rest] = (f < NH) ? Wm[(size_t)f * D * D + rest] : make_float2(0.f, 0.f);
  }
  const int fi = tid & (FT - 1);
  const int o  = tid >> 2;
  const int f  = f0 + fi;
  const int ld = tid >> 2, lf = tid & 3;   // load roles
  for (int b = 0; b < B; ++b) {
    {
      int ff = f0 + lf;
      Ul[ld][lf] = (ff < NH) ? Ubuf[((size_t)b * D + ld) * UST + ff]
                             : make_float2(0.f, 0.f);
    }
    __syncthreads();
    float2 acc = make_float2(0.f, 0.f);
    #pragma unroll
    for (int d2 = 0; d2 < D; ++d2) {
      float2 uu = Ul[d2][fi];
      float2 ww = Wl[fi][d2 * D + o];
      acc.x += uu.x * ww.x - uu.y * ww.y;
      acc.y += uu.x * ww.y + uu.y * ww.x;
    }
    if (f < NH) Qbuf[((size_t)b * D + o) * UST + f] = acc;
    __syncthreads();
  }
}

// ---------------------------------------------------------------- inverse FFT
// block (b*16+q): packed ifft of Y = Q[2q] + i*Q[2q+1]; Hermitian-extend +
// digit-reverse fused into the load. Output dT rows (b*32+2q), (b*32+2q+1).
__global__ __launch_bounds__(512) void k_ifft(const float2* __restrict__ Qbuf,
                                              const float2* __restrict__ tw,
                                              float* __restrict__ dT) {
  __shared__ float sre[4224];
  __shared__ float sim[4224];
  const int blk = blockIdx.x;          // b*16 + q
  const int tid = threadIdx.x;
  const float2* r0 = Qbuf + (size_t)(2 * blk) * UST;
  const float2* r1 = r0 + UST;
  for (int f = tid; f <= 2048; f += 512) {
    float2 q1 = r0[f], q2 = r1[f];
    int pa = PHY(REV4(f));
    int pc = PHY(REV4((NFFT - f) & (NFFT - 1)));
    // Y[f] = q1 + i*q2 ; Y[N-f] = conj(q1) + i*conj(q2)
    sre[pa] = q1.x - q2.y; sim[pa] = q1.y + q2.x;
    sre[pc] = q1.x + q2.y; sim[pc] = -q1.y + q2.x;
  }
  __syncthreads();
  dit6(sre, sim, tw, tid);
  float* d0 = dT + (size_t)(2 * blk) * L;
  float* d1 = d0 + L;
  const float inv = 1.0f / (float)NFFT;
  for (int t = tid; t < L; t += 512) {
    int p = PHY(t);
    d0[t] = sre[p] * inv;
    d1[t] = sim[p] * inv;
  }
}

// ---------------------------------------------------------------- AR term
// delta[b,t,o] = dT[b,o,t] + sum_{k<=min(t,2)} sum_i m_u[o,i,k]*u[b,t-k,i]
#define TT 64
__global__ __launch_bounds__(256) void k_ar(const float* __restrict__ dT,
                                            const float* __restrict__ u,
                                            const float* __restrict__ m_u,
                                            float* __restrict__ delta) {
  __shared__ float Ds[D][TT + 1];
  __shared__ float Us[TT + 2][D];
  __shared__ float Mt[KU][D][D];      // [k][i][o]
  const int b = blockIdx.y;
  const int t0 = blockIdx.x * TT;
  const int tid = threadIdx.x;
  for (int idx = tid; idx < D * D * KU; idx += blockDim.x) {
    int k = idx % KU, i = (idx / KU) % D, o = idx / (KU * D);
    Mt[k][i][o] = m_u[idx];
  }
  for (int idx = tid; idx < D * TT; idx += blockDim.x) {
    int o = idx >> 6, tt = idx & 63;
    Ds[o][tt] = dT[((size_t)b * D + o) * L + t0 + tt];
  }
  for (int idx = tid; idx < (TT + 2) * D; idx += blockDim.x) {
    int j = idx >> 5, i = idx & 31;
    int t = t0 - 2 + j;
    Us[j][i] = (t >= 0) ? u[((size_t)b * L + t) * D + i] : 0.f;
  }
  __syncthreads();
  const int o = tid & 31, ts = tid >> 5;
  for (int tt = ts; tt < TT; tt += 8) {
    int t = t0 + tt;
    float acc = Ds[o][tt];
    #pragma unroll
    for (int k2 = 0; k2 < KU; ++k2) {
      if (t >= k2) {
        const float* ur = Us[tt + 2 - k2];
        #pragma unroll
        for (int i = 0; i < D; ++i) acc += Mt[k2][i][o] * ur[i];
      }
    }
    delta[((size_t)b * L + t) * D + o] = acc;
  }
}

// ---------------------------------------------------------------- recurrence
// Tc = T^64 where T = [[M0, M1], [I, 0]] (6 squarings)
__global__ __launch_bounds__(1024) void k_tc(const float* __restrict__ m_y,
                                             float* __restrict__ Tc) {
  __shared__ float A[64][68];
  __shared__ float Bb[64][68];
  const int tid = threadIdx.x;
  for (int idx = tid; idx < 64 * 64; idx += blockDim.x) {
    int r = idx >> 6, c = idx & 63;
    float v;
    if (r < 32) v = m_y[(r * 2 + (c >> 5)) * D + (c & 31)];
    else        v = (c == r - 32) ? 1.f : 0.f;
    A[r][c] = v;
  }
  __syncthreads();
  const int r = tid >> 4, cg = tid & 15;
  for (int it = 0; it < 6; ++it) {
    float4 acc = make_float4(0.f, 0.f, 0.f, 0.f);
    for (int i = 0; i < 64; ++i) {
      float a = A[r][i];
      float4 v = *(const float4*)&A[i][cg * 4];
      acc.x += a * v.x; acc.y += a * v.y; acc.z += a * v.z; acc.w += a * v.w;
    }
    __syncthreads();
    *(float4*)&Bb[r][cg * 4] = acc;
    __syncthreads();
    *(float4*)&A[r][cg * 4] = *(const float4*)&Bb[r][cg * 4];
    __syncthreads();
  }
  for (int idx = tid; idx < 64 * 64; idx += blockDim.x)
    Tc[idx] = A[idx >> 6][idx & 63];
}

// Phase A: zero-state chunk response; emit shat[b,c] = [y_{C-1}; y_{C-2}]
__global__ void k_scanA(const float* __restrict__ delta,
                        const float* __restrict__ m_y,
                        float* __restrict__ shat) {
  __shared__ float yb[2][D];
  const int b = blockIdx.y, c = blockIdx.x;
  const int lane = threadIdx.x;            // 64 = one wave
  const int o = lane & 31, h = lane >> 5;
  float m0[16], m1[16];
  #pragma unroll
  for (int i = 0; i < 16; ++i) {
    m0[i] = m_y[(o * 2 + 0) * D + h * 16 + i];
    m1[i] = m_y[(o * 2 + 1) * D + h * 16 + i];
  }
  if (lane < D) { yb[0][lane] = 0.f; yb[1][lane] = 0.f; }
  __syncthreads();
  const float* dp = delta + ((size_t)b * L + c * CCH) * D;
  float ylast = 0.f, yprev = 0.f;
  for (int r = 0; r < CCH; ++r) {
    const float* y1 = yb[(r + 1) & 1];
    const float* y2 = yb[r & 1];
    float acc = 0.f;
    #pragma unroll
    for (int i = 0; i < 16; ++i)
      acc += m0[i] * y1[h * 16 + i] + m1[i] * y2[h * 16 + i];
    acc += __shfl_xor(acc, 32);
    float y = acc + dp[r * D + o];
    __syncthreads();
    if (h == 0) yb[r & 1][o] = y;
    __syncthreads();
    yprev = ylast; ylast = y;
  }
  if (h == 0) {
    float* sp = shat + ((size_t)b * NCH + c) * 64;
    sp[o] = ylast;
    sp[32 + o] = yprev;
  }
}

// Phase B: inter-chunk state scan, record incoming state per chunk.
__global__ void k_scanB(const float* __restrict__ Tc,
                        const float* __restrict__ shat,
                        float* __restrict__ sin_) {
  __shared__ float TcT[64][65];
  __shared__ float sb[64];
  const int b = blockIdx.x;
  const int r = threadIdx.x;               // 64
  for (int idx = r; idx < 64 * 64; idx += 64) {
    int rr = idx >> 6, cc = idx & 63;
    TcT[cc][rr] = Tc[idx];
  }
  sb[r] = 0.f;
  __syncthreads();
  for (int c = 0; c < NCH; ++c) {
    sin_[((size_t)b * NCH + c) * 64 + r] = sb[r];
    float acc = 0.f;
    #pragma unroll 8
    for (int i = 0; i < 64; ++i) acc += TcT[i][r] * sb[i];
    acc += shat[((size_t)b * NCH + c) * 64 + r];
    __syncthreads();
    sb[r] = acc;
    __syncthreads();
  }
}

// Phase C: re-run each chunk with true incoming state, write output.
__global__ void k_scanC(const float* __restrict__ delta,
                        const float* __restrict__ m_y,
                        const float* __restrict__ sin_,
                        float* __restrict__ out) {
  __shared__ float yb[2][D];
  const int b = blockIdx.y, c = blockIdx.x;
  const int lane = threadIdx.x;
  const int o = lane & 31, h = lane >> 5;
  float m0[16], m1[16];
  #pragma unroll
  for (int i = 0; i < 16; ++i) {
    m0[i] = m_y[(o * 2 + 0) * D + h * 16 + i];
    m1[i] = m_y[(o * 2 + 1) * D + h * 16 + i];
  }
  const float* sp = sin_ + ((size_t)b * NCH + c) * 64;
  if (lane < 32) yb[1][lane] = sp[lane];        // y_{-1}
  else           yb[0][lane - 32] = sp[lane];   // y_{-2}
  __syncthreads();
  const float* dp = delta + ((size_t)b * L + c * CCH) * D;
  float* op = out + ((size_t)b * L + c * CCH) * D;
  for (int r = 0; r < CCH; ++r) {
    const float* y1 = yb[(r + 1) & 1];
    const float* y2 = yb[r & 1];
    float acc = 0.f;
    #pragma unroll
    for (int i = 0; i < 16; ++i)
      acc += m0[i] * y1[h * 16 + i] + m1[i] * y2[h * 16 + i];
    acc += __shfl_xor(acc, 32);
    float y = acc + dp[r * D + o];
    __syncthreads();
    if (h == 0) { yb[r & 1][o] = y; op[r * D + o] = y; }
    __syncthreads();
  }
}

// ---------------------------------------------------------------- launch
extern "C" void kernel_launch(void* const* d_in, const int* in_sizes, int n_in,
                              void* d_out, int out_size, void* d_ws, size_t ws_size,
                              hipStream_t stream) {
  const float* u        = (const float*)d_in[0];
  const float* eig_vals = (const float*)d_in[1];
  const float* eig_vecs = (const float*)d_in[2];
  const float* m_u      = (const float*)d_in[3];
  const float* m_phi    = (const float*)d_in[4];
  const float* m_y      = (const float*)d_in[5];
  float* out = (float*)d_out;

  char* ws = (char*)d_ws;
  size_t off = 0;
  auto alloc = [&](size_t bytes) -> void* {
    void* p = ws + off;
    off += bytes;
    off = (off + 255) & ~(size_t)255;
    return p;
  };
  float2* tw   = (float2*)alloc((size_t)NFFT * sizeof(float2));           // 32 KB
  float2* uTp  = (float2*)alloc((size_t)B * 16 * L * sizeof(float2));     // 8.4 MB
  float2* Vf   = (float2*)alloc((size_t)D * UST * sizeof(float2));        // 0.5 MB
  float2* Wm   = (float2*)alloc((size_t)NH * D * D * sizeof(float2));     // 16.8 MB
  float2* Ubuf = (float2*)alloc((size_t)B * D * UST * sizeof(float2));    // 16.8 MB
  float2* Qbuf = (float2*)alloc((size_t)B * D * UST * sizeof(float2));    // 16.8 MB
  float*  Tc   = (float*)alloc(64 * 64 * sizeof(float));
  float*  shat = (float*)alloc((size_t)B * NCH * 64 * sizeof(float));
  float*  sinb = (float*)alloc((size_t)B * NCH * 64 * sizeof(float));
  // aliases: dT reuses uTp (dead after k_fft_fwd); delta reuses Ubuf (dead after k_mix)
  float* dT    = (float*)uTp;
  float* delta = (float*)Ubuf;

  k_init_tw<<<16, 256, 0, stream>>>(tw);
  k_tr     <<<dim3(L / 64, B), 256, 0, stream>>>(u, uTp);
  k_fft_fwd<<<528, 512, 0, stream>>>(uTp, eig_vecs, eig_vals, tw, Ubuf, Vf);
  k_w      <<<NH, 1024, 0, stream>>>(Vf, m_phi, Wm);
  k_mix    <<<(NH + FT - 1) / FT, 128, 0, stream>>>(Ubuf, Wm, Qbuf);
  k_ifft   <<<B * 16, 512, 0, stream>>>(Qbuf, tw, dT);
  k_ar     <<<dim3(L / TT, B), 256, 0, stream>>>(dT, u, m_u, delta);
  k_tc     <<<1, 1024, 0, stream>>>(m_y, Tc);
  k_scanA  <<<dim3(NCH, B), 64, 0, stream>>>(delta, m_y, shat);
  k_scanB  <<<B, 64, 0, stream>>>(Tc, shat, sinb);
  k_scanC  <<<dim3(NCH, B), 64, 0, stream>>>(delta, m_y, sinb, out);
}

// Round 6
// 278.640 us; speedup vs baseline: 1.3290x; 1.1018x over previous
//
#include <hip/hip_runtime.h>
#include <math.h>

#define L     2048
#define NFFT  4096
#define NH    2049          // half-spectrum bins
#define UST   2052          // row stride (in float2) for half-spectrum rows
#define D     32
#define B     32
#define KU    3
#define CCH   64            // recurrence chunk length
#define NCH   32            // L / CCH

// skewed LDS physical address (pad 1 float per 32)
__device__ __forceinline__ int PHY(int i) { return i + (i >> 5); }
// base-4 digit reversal of a 12-bit index
__device__ __forceinline__ int REV4(int i) {
  int r2 = __brev(i) >> 20;
  return ((r2 & 0x555) << 1) | ((r2 >> 1) & 0x555);
}

// ---------------------------------------------------------------- twiddles
__global__ void k_init_tw(float2* __restrict__ tw) {
  int j = blockIdx.x * blockDim.x + threadIdx.x;
  if (j < NFFT) {
    double ang = -2.0 * 3.14159265358979323846 * (double)j / (double)NFFT;
    tw[j] = make_float2((float)cos(ang), (float)sin(ang));
  }
}

// ---------------------------------------------------------------- FFT cores
// Forward: 6 in-place radix-4 DIF stages. Natural in -> base4-digit-reversed out.
__device__ void dif6(float* sre, float* sim, const float2* __restrict__ tw, int tid) {
  #pragma unroll
  for (int st = 0; st < 6; ++st) {
    const int shift = 10 - 2 * st;       // log2(q), q = 1024 >> 2st
    const int q = 1 << shift;
    const int r = 1 << (2 * st);         // N/(4q)
    #pragma unroll
    for (int h = 0; h < 2; ++h) {
      const int idx = tid + h * 512;
      const int j = idx & (q - 1);
      const int g = idx >> shift;
      const int i0 = (g << (shift + 2)) + j;
      const int p0 = PHY(i0), p1 = PHY(i0 + q), p2 = PHY(i0 + 2 * q), p3 = PHY(i0 + 3 * q);
      float ax = sre[p0], ay = sim[p0], bx = sre[p1], by = sim[p1];
      float cx = sre[p2], cy = sim[p2], dx = sre[p3], dy = sim[p3];
      float t0x = ax + cx, t0y = ay + cy, t1x = ax - cx, t1y = ay - cy;
      float t2x = bx + dx, t2y = by + dy, t3x = bx - dx, t3y = by - dy;
      float2 w1 = tw[j * r];
      float w2x = w1.x * w1.x - w1.y * w1.y, w2y = 2.f * w1.x * w1.y;
      float w3x = w2x * w1.x - w2y * w1.y, w3y = w2x * w1.y + w2y * w1.x;
      sre[p0] = t0x + t2x; sim[p0] = t0y + t2y;
      float u1x = t1x + t3y, u1y = t1y - t3x;              // t1 - i*t3
      sre[p1] = u1x * w1.x - u1y * w1.y; sim[p1] = u1x * w1.y + u1y * w1.x;
      float u2x = t0x - t2x, u2y = t0y - t2y;
      sre[p2] = u2x * w2x - u2y * w2y; sim[p2] = u2x * w2y + u2y * w2x;
      float u3x = t1x - t3y, u3y = t1y + t3x;              // t1 + i*t3
      sre[p3] = u3x * w3x - u3y * w3y; sim[p3] = u3x * w3y + u3y * w3x;
    }
    __syncthreads();
  }
}

// Inverse: 6 in-place radix-4 DIT stages (transpose of DIF with conj twiddles).
// base4-digit-reversed in -> natural out. No 1/N scaling here.
__device__ void dit6(float* sre, float* sim, const float2* __restrict__ tw, int tid) {
  #pragma unroll
  for (int st = 0; st < 6; ++st) {
    const int shift = 2 * st;            // log2(q), q = 1<<2st
    const int q = 1 << shift;
    const int r = 1 << (10 - 2 * st);
    #pragma unroll
    for (int h = 0; h < 2; ++h) {
      const int idx = tid + h * 512;
      const int j = idx & (q - 1);
      const int g = idx >> shift;
      const int i0 = (g << (shift + 2)) + j;
      const int p0 = PHY(i0), p1 = PHY(i0 + q), p2 = PHY(i0 + 2 * q), p3 = PHY(i0 + 3 * q);
      float ax = sre[p0], ay = sim[p0], bx = sre[p1], by = sim[p1];
      float cx = sre[p2], cy = sim[p2], dx = sre[p3], dy = sim[p3];
      float2 w1 = tw[j * r]; w1.y = -w1.y;                 // conj
      float w2x = w1.x * w1.x - w1.y * w1.y, w2y = 2.f * w1.x * w1.y;
      float w3x = w2x * w1.x - w2y * w1.y, w3y = w2x * w1.y + w2y * w1.x;
      float bpx = bx * w1.x - by * w1.y, bpy = bx * w1.y + by * w1.x;
      float cpx = cx * w2x - cy * w2y,   cpy = cx * w2y + cy * w2x;
      float dpx = dx * w3x - dy * w3y,   dpy = dx * w3y + dy * w3x;
      float t0x = ax + cpx, t0y = ay + cpy, t1x = ax - cpx, t1y = ay - cpy;
      float t2x = bpx + dpx, t2y = bpy + dpy, t3x = bpx - dpx, t3y = bpy - dpy;
      sre[p0] = t0x + t2x; sim[p0] = t0y + t2y;
      sre[p1] = t1x - t3y; sim[p1] = t1y + t3x;            // t1 + i*t3
      sre[p2] = t0x - t2x; sim[p2] = t0y - t2y;
      sre[p3] = t1x + t3y; sim[p3] = t1y - t3x;            // t1 - i*t3
    }
    __syncthreads();
  }
}

// ---------------------------------------------------------------- transpose u
// u (b, t, d) -> uTp rows (b*16+p) of float2 { u[t][2p], u[t][2p+1] }, t-major.
__global__ __launch_bounds__(256) void k_tr(const float* __restrict__ u,
                                            float2* __restrict__ uTp) {
  __shared__ float tile[64][33];
  const int b = blockIdx.y;
  const int t0 = blockIdx.x * 64;
  const int tid = threadIdx.x;
  for (int i = tid; i < 64 * 32; i += 256) {
    int tl = i >> 5, d = i & 31;
    tile[tl][d] = u[((size_t)b * L + t0 + tl) * D + d];
  }
  __syncthreads();
  for (int i = tid; i < 16 * 64; i += 256) {
    int p = i >> 6, tt = i & 63;
    uTp[((size_t)b * 16 + p) * L + t0 + tt] =
        make_float2(tile[tt][2 * p], tile[tt][2 * p + 1]);
  }
}

// ---------------------------------------------------------------- forward FFT
// blocks 0..511: u-pack (b,p): FFT of z = u[:,2p] + i*u[:,2p+1], unpack ->
//   Ubuf rows (b*32+2p), (b*32+2p+1), half-spectrum f<=2048.
// blocks 512..527: eigvec pack p2: unpack + eigval^0.25 scale -> Vf rows.
__global__ __launch_bounds__(512) void k_fft_fwd(const float2* __restrict__ uTp,
                                                 const float* __restrict__ eig_vecs,
                                                 const float* __restrict__ eig_vals,
                                                 const float2* __restrict__ tw,
                                                 float2* __restrict__ Ubuf,
                                                 float2* __restrict__ Vf) {
  __shared__ float sre[4224];
  __shared__ float sim[4224];
  const int blk = blockIdx.x;
  const int tid = threadIdx.x;
  if (blk < 512) {
    const float2* zp = uTp + (size_t)blk * L;
    for (int t = tid; t < L; t += 512) {
      float2 z = zp[t];
      int p = PHY(t);
      sre[p] = z.x; sim[p] = z.y;
    }
  } else {
    const int p2 = blk - 512;
    for (int t = tid; t < L; t += 512) {
      int p = PHY(t);
      sre[p] = eig_vecs[(size_t)t * D + 2 * p2];
      sim[p] = eig_vecs[(size_t)t * D + 2 * p2 + 1];
    }
  }
  for (int t = L + tid; t < NFFT; t += 512) {
    int p = PHY(t);
    sre[p] = 0.f; sim[p] = 0.f;
  }
  __syncthreads();
  dif6(sre, sim, tw, tid);
  // unpack: U_even = (A + conj(Ac))/2 ; U_odd = -i*(A - conj(Ac))/2
  if (blk < 512) {
    float2* r0 = Ubuf + (size_t)(2 * blk) * UST;       // row (b*32 + 2p)
    float2* r1 = r0 + UST;
    for (int f = tid; f <= 2048; f += 512) {
      int pa = PHY(REV4(f));
      int pc = PHY(REV4((NFFT - f) & (NFFT - 1)));
      float Ax = sre[pa], Ay = sim[pa];
      float Bx = sre[pc], By = -sim[pc];
      r0[f] = make_float2(0.5f * (Ax + Bx), 0.5f * (Ay + By));
      float Dx = Ax - Bx, Dy = Ay - By;
      r1[f] = make_float2(0.5f * Dy, -0.5f * Dx);
    }
  } else {
    const int p2 = blk - 512;
    const float sc0 = powf(eig_vals[2 * p2], 0.25f);
    const float sc1 = powf(eig_vals[2 * p2 + 1], 0.25f);
    float2* r0 = Vf + (size_t)(2 * p2) * UST;
    float2* r1 = r0 + UST;
    for (int f = tid; f <= 2048; f += 512) {
      int pa = PHY(REV4(f));
      int pc = PHY(REV4((NFFT - f) & (NFFT - 1)));
      float Ax = sre[pa], Ay = sim[pa];
      float Bx = sre[pc], By = -sim[pc];
      r0[f] = make_float2(0.5f * sc0 * (Ax + Bx), 0.5f * sc0 * (Ay + By));
      float Dx = Ax - Bx, Dy = Ay - By;
      r1[f] = make_float2(0.5f * sc1 * Dy, -0.5f * sc1 * Dx);
    }
  }
}

// ---------------------------------------------------------------- W build
// Wm[f,d,o] = sum_k Vf[k][f] * m_phi[k*32+d, o]
__global__ __launch_bounds__(1024) void k_w(const float2* __restrict__ Vf,
                                            const float* __restrict__ m_phi,
                                            float2* __restrict__ Wm) {
  __shared__ float2 vl[D];
  const int f = blockIdx.x, tid = threadIdx.x;
  if (tid < D) vl[tid] = Vf[(size_t)tid * UST + f];
  __syncthreads();
  const int d = tid >> 5, o = tid & 31;
  float2 acc = make_float2(0.f, 0.f);
  #pragma unroll
  for (int k = 0; k < D; ++k) {
    float m = m_phi[(k * D + d) * D + o];
    float2 v = vl[k];
    acc.x += v.x * m;
    acc.y += v.y * m;
  }
  Wm[(size_t)f * D * D + d * D + o] = acc;
}

// ---------------------------------------------------------------- mix v2
// Q[b,o,f] = sum_d Ubuf[b,d,f] * Wm[f,d,o], half-spectrum only.
// Block: 256 threads = 32 o x 8 fi, FT=8 freqs. W in registers (thread
// (fi,o) owns W[f][*][o]); U staged per 8-batch chunk (broadcast reads);
// output staged in swizzled LDS tile for coalesced row writes.
#define FT 8
#define BC 8
__global__ __launch_bounds__(256) void k_mix(const float2* __restrict__ Ubuf,
                                             const float2* __restrict__ Wm,
                                             float2* __restrict__ Qbuf) {
  __shared__ float2 Ul[BC][D][FT];
  __shared__ float2 Qs[BC][D][FT];
  const int f0 = blockIdx.x * FT;
  const int tid = threadIdx.x;
  const int o = tid & 31, fi = tid >> 5;
  const int f = f0 + fi;
  // W fragment into registers: Wr[d] = Wm[f][d][o] (coalesced across o)
  float2 Wr[D];
  if (f < NH) {
    const float2* wp = Wm + (size_t)f * D * D + o;
    #pragma unroll
    for (int d = 0; d < D; ++d) Wr[d] = wp[d * D];
  } else {
    #pragma unroll
    for (int d = 0; d < D; ++d) Wr[d] = make_float2(0.f, 0.f);
  }
  const int lf = tid & 7, row = tid >> 3;      // load/store roles
  for (int b0 = 0; b0 < B; b0 += BC) {
    // stage U chunk: rows (b0+bc)*32+d, cols f0..f0+7 (64B per 8-lane group)
    #pragma unroll
    for (int it = 0; it < 8; ++it) {
      int r = row + it * 32;                   // 0..255
      int bc = r >> 5, d = r & 31;
      int ff = f0 + lf;
      Ul[bc][d][lf] = (ff < NH)
          ? Ubuf[((size_t)(b0 + bc) * D + d) * UST + ff]
          : make_float2(0.f, 0.f);
    }
    __syncthreads();
    // compute: thread (fi,o) does Q[b0+bc][o][f] = sum_d Ul[bc][d][fi]*Wr[d]
    #pragma unroll
    for (int bc = 0; bc < BC; ++bc) {
      float ax = 0.f, ay = 0.f;
      #pragma unroll
      for (int d = 0; d < D; ++d) {
        float2 uu = Ul[bc][d][fi];
        float2 ww = Wr[d];
        ax += uu.x * ww.x - uu.y * ww.y;
        ay += uu.x * ww.y + uu.y * ww.x;
      }
      Qs[bc][o][(fi + o) & 7] = make_float2(ax, ay);   // swizzled store
    }
    __syncthreads();
    // write out coalesced: row (b0+bc)*32+oo, cols f0..f0+7
    #pragma unroll
    for (int it = 0; it < 8; ++it) {
      int r = row + it * 32;
      int bc = r >> 5, oo = r & 31;
      int ff = f0 + lf;
      if (ff < NH)
        Qbuf[((size_t)(b0 + bc) * D + oo) * UST + ff] = Qs[bc][oo][(lf + oo) & 7];
    }
    // next iteration's Ul stage is fenced from this chunk's compute reads by
    // the barrier above; compute(n+1)'s Qs writes are fenced from these reads
    // by the barrier at the top of the next loop body:
    __syncthreads();
  }
}

// ---------------------------------------------------------------- inverse FFT
// block (b*16+q): packed ifft of Y = Q[2q] + i*Q[2q+1]; Hermitian-extend +
// digit-reverse fused into the load. Output dT rows (b*32+2q), (b*32+2q+1).
__global__ __launch_bounds__(512) void k_ifft(const float2* __restrict__ Qbuf,
                                              const float2* __restrict__ tw,
                                              float* __restrict__ dT) {
  __shared__ float sre[4224];
  __shared__ float sim[4224];
  const int blk = blockIdx.x;          // b*16 + q
  const int tid = threadIdx.x;
  const float2* r0 = Qbuf + (size_t)(2 * blk) * UST;
  const float2* r1 = r0 + UST;
  for (int f = tid; f <= 2048; f += 512) {
    float2 q1 = r0[f], q2 = r1[f];
    int pa = PHY(REV4(f));
    int pc = PHY(REV4((NFFT - f) & (NFFT - 1)));
    // Y[f] = q1 + i*q2 ; Y[N-f] = conj(q1) + i*conj(q2)
    sre[pa] = q1.x - q2.y; sim[pa] = q1.y + q2.x;
    sre[pc] = q1.x + q2.y; sim[pc] = -q1.y + q2.x;
  }
  __syncthreads();
  dit6(sre, sim, tw, tid);
  float* d0 = dT + (size_t)(2 * blk) * L;
  float* d1 = d0 + L;
  const float inv = 1.0f / (float)NFFT;
  for (int t = tid; t < L; t += 512) {
    int p = PHY(t);
    d0[t] = sre[p] * inv;
    d1[t] = sim[p] * inv;
  }
}

// ---------------------------------------------------------------- AR term
// delta[b,t,o] = dT[b,o,t] + sum_{k<=min(t,2)} sum_i m_u[o,i,k]*u[b,t-k,i]
#define TT 64
__global__ __launch_bounds__(256) void k_ar(const float* __restrict__ dT,
                                            const float* __restrict__ u,
                                            const float* __restrict__ m_u,
                                            float* __restrict__ delta) {
  __shared__ float Ds[D][TT + 1];
  __shared__ float Us[TT + 2][D];
  __shared__ float Mt[KU][D][D];      // [k][i][o]
  const int b = blockIdx.y;
  const int t0 = blockIdx.x * TT;
  const int tid = threadIdx.x;
  for (int idx = tid; idx < D * D * KU; idx += blockDim.x) {
    int k = idx % KU, i = (idx / KU) % D, o = idx / (KU * D);
    Mt[k][i][o] = m_u[idx];
  }
  for (int idx = tid; idx < D * TT; idx += blockDim.x) {
    int o = idx >> 6, tt = idx & 63;
    Ds[o][tt] = dT[((size_t)b * D + o) * L + t0 + tt];
  }
  for (int idx = tid; idx < (TT + 2) * D; idx += blockDim.x) {
    int j = idx >> 5, i = idx & 31;
    int t = t0 - 2 + j;
    Us[j][i] = (t >= 0) ? u[((size_t)b * L + t) * D + i] : 0.f;
  }
  __syncthreads();
  const int o = tid & 31, ts = tid >> 5;
  for (int tt = ts; tt < TT; tt += 8) {
    int t = t0 + tt;
    float acc = Ds[o][tt];
    #pragma unroll
    for (int k2 = 0; k2 < KU; ++k2) {
      if (t >= k2) {
        const float* ur = Us[tt + 2 - k2];
        #pragma unroll
        for (int i = 0; i < D; ++i) acc += Mt[k2][i][o] * ur[i];
      }
    }
    delta[((size_t)b * L + t) * D + o] = acc;
  }
}

// ---------------------------------------------------------------- recurrence
// Tc = T^64 where T = [[M0, M1], [I, 0]] (6 squarings)
__global__ __launch_bounds__(1024) void k_tc(const float* __restrict__ m_y,
                                             float* __restrict__ Tc) {
  __shared__ float A[64][68];
  __shared__ float Bb[64][68];
  const int tid = threadIdx.x;
  for (int idx = tid; idx < 64 * 64; idx += blockDim.x) {
    int r = idx >> 6, c = idx & 63;
    float v;
    if (r < 32) v = m_y[(r * 2 + (c >> 5)) * D + (c & 31)];
    else        v = (c == r - 32) ? 1.f : 0.f;
    A[r][c] = v;
  }
  __syncthreads();
  const int r = tid >> 4, cg = tid & 15;
  for (int it = 0; it < 6; ++it) {
    float4 acc = make_float4(0.f, 0.f, 0.f, 0.f);
    for (int i = 0; i < 64; ++i) {
      float a = A[r][i];
      float4 v = *(const float4*)&A[i][cg * 4];
      acc.x += a * v.x; acc.y += a * v.y; acc.z += a * v.z; acc.w += a * v.w;
    }
    __syncthreads();
    *(float4*)&Bb[r][cg * 4] = acc;
    __syncthreads();
    *(float4*)&A[r][cg * 4] = *(const float4*)&Bb[r][cg * 4];
    __syncthreads();
  }
  for (int idx = tid; idx < 64 * 64; idx += blockDim.x)
    Tc[idx] = A[idx >> 6][idx & 63];
}

// Phase A: zero-state chunk response; emit shat[b,c] = [y_{C-1}; y_{C-2}]
__global__ void k_scanA(const float* __restrict__ delta,
                        const float* __restrict__ m_y,
                        float* __restrict__ shat) {
  __shared__ float yb[2][D];
  const int b = blockIdx.y, c = blockIdx.x;
  const int lane = threadIdx.x;            // 64 = one wave
  const int o = lane & 31, h = lane >> 5;
  float m0[16], m1[16];
  #pragma unroll
  for (int i = 0; i < 16; ++i) {
    m0[i] = m_y[(o * 2 + 0) * D + h * 16 + i];
    m1[i] = m_y[(o * 2 + 1) * D + h * 16 + i];
  }
  if (lane < D) { yb[0][lane] = 0.f; yb[1][lane] = 0.f; }
  __syncthreads();
  const float* dp = delta + ((size_t)b * L + c * CCH) * D;
  float ylast = 0.f, yprev = 0.f;
  for (int r = 0; r < CCH; ++r) {
    const float* y1 = yb[(r + 1) & 1];
    const float* y2 = yb[r & 1];
    float acc = 0.f;
    #pragma unroll
    for (int i = 0; i < 16; ++i)
      acc += m0[i] * y1[h * 16 + i] + m1[i] * y2[h * 16 + i];
    acc += __shfl_xor(acc, 32);
    float y = acc + dp[r * D + o];
    __syncthreads();
    if (h == 0) yb[r & 1][o] = y;
    __syncthreads();
    yprev = ylast; ylast = y;
  }
  if (h == 0) {
    float* sp = shat + ((size_t)b * NCH + c) * 64;
    sp[o] = ylast;
    sp[32 + o] = yprev;
  }
}

// Phase B: inter-chunk state scan, record incoming state per chunk.
__global__ void k_scanB(const float* __restrict__ Tc,
                        const float* __restrict__ shat,
                        float* __restrict__ sin_) {
  __shared__ float TcT[64][65];
  __shared__ float sb[64];
  const int b = blockIdx.x;
  const int r = threadIdx.x;               // 64
  for (int idx = r; idx < 64 * 64; idx += 64) {
    int rr = idx >> 6, cc = idx & 63;
    TcT[cc][rr] = Tc[idx];
  }
  sb[r] = 0.f;
  __syncthreads();
  for (int c = 0; c < NCH; ++c) {
    sin_[((size_t)b * NCH + c) * 64 + r] = sb[r];
    float acc = 0.f;
    #pragma unroll 8
    for (int i = 0; i < 64; ++i) acc += TcT[i][r] * sb[i];
    acc += shat[((size_t)b * NCH + c) * 64 + r];
    __syncthreads();
    sb[r] = acc;
    __syncthreads();
  }
}

// Phase C: re-run each chunk with true incoming state, write output.
__global__ void k_scanC(const float* __restrict__ delta,
                        const float* __restrict__ m_y,
                        const float* __restrict__ sin_,
                        float* __restrict__ out) {
  __shared__ float yb[2][D];
  const int b = blockIdx.y, c = blockIdx.x;
  const int lane = threadIdx.x;
  const int o = lane & 31, h = lane >> 5;
  float m0[16], m1[16];
  #pragma unroll
  for (int i = 0; i < 16; ++i) {
    m0[i] = m_y[(o * 2 + 0) * D + h * 16 + i];
    m1[i] = m_y[(o * 2 + 1) * D + h * 16 + i];
  }
  const float* sp = sin_ + ((size_t)b * NCH + c) * 64;
  if (lane < 32) yb[1][lane] = sp[lane];        // y_{-1}
  else           yb[0][lane - 32] = sp[lane];   // y_{-2}
  __syncthreads();
  const float* dp = delta + ((size_t)b * L + c * CCH) * D;
  float* op = out + ((size_t)b * L + c * CCH) * D;
  for (int r = 0; r < CCH; ++r) {
    const float* y1 = yb[(r + 1) & 1];
    const float* y2 = yb[r & 1];
    float acc = 0.f;
    #pragma unroll
    for (int i = 0; i < 16; ++i)
      acc += m0[i] * y1[h * 16 + i] + m1[i] * y2[h * 16 + i];
    acc += __shfl_xor(acc, 32);
    float y = acc + dp[r * D + o];
    __syncthreads();
    if (h == 0) { yb[r & 1][o] = y; op[r * D + o] = y; }
    __syncthreads();
  }
}

// ---------------------------------------------------------------- launch
extern "C" void kernel_launch(void* const* d_in, const int* in_sizes, int n_in,
                              void* d_out, int out_size, void* d_ws, size_t ws_size,
                              hipStream_t stream) {
  const float* u        = (const float*)d_in[0];
  const float* eig_vals = (const float*)d_in[1];
  const float* eig_vecs = (const float*)d_in[2];
  const float* m_u      = (const float*)d_in[3];
  const float* m_phi    = (const float*)d_in[4];
  const float* m_y      = (const float*)d_in[5];
  float* out = (float*)d_out;

  char* ws = (char*)d_ws;
  size_t off = 0;
  auto alloc = [&](size_t bytes) -> void* {
    void* p = ws + off;
    off += bytes;
    off = (off + 255) & ~(size_t)255;
    return p;
  };
  float2* tw   = (float2*)alloc((size_t)NFFT * sizeof(float2));           // 32 KB
  float2* uTp  = (float2*)alloc((size_t)B * 16 * L * sizeof(float2));     // 8.4 MB
  float2* Vf   = (float2*)alloc((size_t)D * UST * sizeof(float2));        // 0.5 MB
  float2* Wm   = (float2*)alloc((size_t)NH * D * D * sizeof(float2));     // 16.8 MB
  float2* Ubuf = (float2*)alloc((size_t)B * D * UST * sizeof(float2));    // 16.8 MB
  float2* Qbuf = (float2*)alloc((size_t)B * D * UST * sizeof(float2));    // 16.8 MB
  float*  Tc   = (float*)alloc(64 * 64 * sizeof(float));
  float*  shat = (float*)alloc((size_t)B * NCH * 64 * sizeof(float));
  float*  sinb = (float*)alloc((size_t)B * NCH * 64 * sizeof(float));
  // aliases: dT reuses uTp (dead after k_fft_fwd); delta reuses Ubuf (dead after k_mix)
  float* dT    = (float*)uTp;
  float* delta = (float*)Ubuf;

  k_init_tw<<<16, 256, 0, stream>>>(tw);
  k_tr     <<<dim3(L / 64, B), 256, 0, stream>>>(u, uTp);
  k_fft_fwd<<<528, 512, 0, stream>>>(uTp, eig_vecs, eig_vals, tw, Ubuf, Vf);
  k_w      <<<NH, 1024, 0, stream>>>(Vf, m_phi, Wm);
  k_mix    <<<(NH + FT - 1) / FT, 256, 0, stream>>>(Ubuf, Wm, Qbuf);
  k_ifft   <<<B * 16, 512, 0, stream>>>(Qbuf, tw, dT);
  k_ar     <<<dim3(L / TT, B), 256, 0, stream>>>(dT, u, m_u, delta);
  k_tc     <<<1, 1024, 0, stream>>>(m_y, Tc);
  k_scanA  <<<dim3(NCH, B), 64, 0, stream>>>(delta, m_y, shat);
  k_scanB  <<<B, 64, 0, stream>>>(Tc, shat, sinb);
  k_scanC  <<<dim3(NCH, B), 64, 0, stream>>>(delta, m_y, sinb, out);
}

// Round 7
// 271.120 us; speedup vs baseline: 1.3659x; 1.0277x over previous
//
#include <hip/hip_runtime.h>
#include <math.h>

#define L     2048
#define NFFT  4096
#define NH    2049          // half-spectrum bins
#define UST   2052          // row stride (in float2) for half-spectrum rows
#define D     32
#define B     32
#define KU    3
#define CCH   64            // recurrence chunk length
#define NCH   32            // L / CCH

// skewed LDS physical address (pad 1 float per 32)
__device__ __forceinline__ int PHY(int i) { return i + (i >> 5); }
// base-4 digit reversal of a 12-bit index
__device__ __forceinline__ int REV4(int i) {
  int r2 = __brev(i) >> 20;
  return ((r2 & 0x555) << 1) | ((r2 >> 1) & 0x555);
}

// ---------------------------------------------------------------- FFT cores
// Forward: 6 in-place radix-4 DIF stages. Natural in -> base4-digit-reversed out.
__device__ void dif6(float* sre, float* sim, const float2* __restrict__ tw, int tid) {
  #pragma unroll
  for (int st = 0; st < 6; ++st) {
    const int shift = 10 - 2 * st;       // log2(q), q = 1024 >> 2st
    const int q = 1 << shift;
    const int r = 1 << (2 * st);         // N/(4q)
    #pragma unroll
    for (int h = 0; h < 2; ++h) {
      const int idx = tid + h * 512;
      const int j = idx & (q - 1);
      const int g = idx >> shift;
      const int i0 = (g << (shift + 2)) + j;
      const int p0 = PHY(i0), p1 = PHY(i0 + q), p2 = PHY(i0 + 2 * q), p3 = PHY(i0 + 3 * q);
      float ax = sre[p0], ay = sim[p0], bx = sre[p1], by = sim[p1];
      float cx = sre[p2], cy = sim[p2], dx = sre[p3], dy = sim[p3];
      float t0x = ax + cx, t0y = ay + cy, t1x = ax - cx, t1y = ay - cy;
      float t2x = bx + dx, t2y = by + dy, t3x = bx - dx, t3y = by - dy;
      float2 w1 = tw[j * r];
      float w2x = w1.x * w1.x - w1.y * w1.y, w2y = 2.f * w1.x * w1.y;
      float w3x = w2x * w1.x - w2y * w1.y, w3y = w2x * w1.y + w2y * w1.x;
      sre[p0] = t0x + t2x; sim[p0] = t0y + t2y;
      float u1x = t1x + t3y, u1y = t1y - t3x;              // t1 - i*t3
      sre[p1] = u1x * w1.x - u1y * w1.y; sim[p1] = u1x * w1.y + u1y * w1.x;
      float u2x = t0x - t2x, u2y = t0y - t2y;
      sre[p2] = u2x * w2x - u2y * w2y; sim[p2] = u2x * w2y + u2y * w2x;
      float u3x = t1x - t3y, u3y = t1y + t3x;              // t1 + i*t3
      sre[p3] = u3x * w3x - u3y * w3y; sim[p3] = u3x * w3y + u3y * w3x;
    }
    __syncthreads();
  }
}

// Inverse: 6 in-place radix-4 DIT stages (transpose of DIF with conj twiddles).
// base4-digit-reversed in -> natural out. No 1/N scaling here.
__device__ void dit6(float* sre, float* sim, const float2* __restrict__ tw, int tid) {
  #pragma unroll
  for (int st = 0; st < 6; ++st) {
    const int shift = 2 * st;            // log2(q), q = 1<<2st
    const int q = 1 << shift;
    const int r = 1 << (10 - 2 * st);
    #pragma unroll
    for (int h = 0; h < 2; ++h) {
      const int idx = tid + h * 512;
      const int j = idx & (q - 1);
      const int g = idx >> shift;
      const int i0 = (g << (shift + 2)) + j;
      const int p0 = PHY(i0), p1 = PHY(i0 + q), p2 = PHY(i0 + 2 * q), p3 = PHY(i0 + 3 * q);
      float ax = sre[p0], ay = sim[p0], bx = sre[p1], by = sim[p1];
      float cx = sre[p2], cy = sim[p2], dx = sre[p3], dy = sim[p3];
      float2 w1 = tw[j * r]; w1.y = -w1.y;                 // conj
      float w2x = w1.x * w1.x - w1.y * w1.y, w2y = 2.f * w1.x * w1.y;
      float w3x = w2x * w1.x - w2y * w1.y, w3y = w2x * w1.y + w2y * w1.x;
      float bpx = bx * w1.x - by * w1.y, bpy = bx * w1.y + by * w1.x;
      float cpx = cx * w2x - cy * w2y,   cpy = cx * w2y + cy * w2x;
      float dpx = dx * w3x - dy * w3y,   dpy = dx * w3y + dy * w3x;
      float t0x = ax + cpx, t0y = ay + cpy, t1x = ax - cpx, t1y = ay - cpy;
      float t2x = bpx + dpx, t2y = bpy + dpy, t3x = bpx - dpx, t3y = bpy - dpy;
      sre[p0] = t0x + t2x; sim[p0] = t0y + t2y;
      sre[p1] = t1x - t3y; sim[p1] = t1y + t3x;            // t1 + i*t3
      sre[p2] = t0x - t2x; sim[p2] = t0y - t2y;
      sre[p3] = t1x + t3y; sim[p3] = t1y - t3x;            // t1 - i*t3
    }
    __syncthreads();
  }
}

// ---------------------------------------------------------------- transpose u (+ tw init)
// u (b, t, d) -> uTp rows (b*16+p) of float2 { u[t][2p], u[t][2p+1] }, t-major.
// Extra blocks (bx >= L/64, b==0) fill the twiddle table.
__global__ __launch_bounds__(256) void k_tr(const float* __restrict__ u,
                                            float2* __restrict__ uTp,
                                            float2* __restrict__ tw) {
  const int bx = blockIdx.x;
  const int b = blockIdx.y;
  const int tid = threadIdx.x;
  if (bx >= L / 64) {
    if (b == 0) {
      for (int jj = tid; jj < 2048; jj += 256) {
        int j = (bx - L / 64) * 2048 + jj;
        double ang = -2.0 * 3.14159265358979323846 * (double)j / (double)NFFT;
        tw[j] = make_float2((float)cos(ang), (float)sin(ang));
      }
    }
    return;
  }
  __shared__ float tile[64][33];
  const int t0 = bx * 64;
  for (int i = tid; i < 64 * 32; i += 256) {
    int tl = i >> 5, d = i & 31;
    tile[tl][d] = u[((size_t)b * L + t0 + tl) * D + d];
  }
  __syncthreads();
  for (int i = tid; i < 16 * 64; i += 256) {
    int p = i >> 6, tt = i & 63;
    uTp[((size_t)b * 16 + p) * L + t0 + tt] =
        make_float2(tile[tt][2 * p], tile[tt][2 * p + 1]);
  }
}

// ---------------------------------------------------------------- forward FFT
// blocks 0..511: u-pack (b,p): FFT of z = u[:,2p] + i*u[:,2p+1], unpack ->
//   Ubuf rows (b*32+2p), (b*32+2p+1), half-spectrum f<=2048.
// blocks 512..527: eigvec pack p2: unpack + eigval^0.25 scale -> Vf rows.
__global__ __launch_bounds__(512) void k_fft_fwd(const float2* __restrict__ uTp,
                                                 const float* __restrict__ eig_vecs,
                                                 const float* __restrict__ eig_vals,
                                                 const float2* __restrict__ tw,
                                                 float2* __restrict__ Ubuf,
                                                 float2* __restrict__ Vf) {
  __shared__ float sre[4224];
  __shared__ float sim[4224];
  const int blk = blockIdx.x;
  const int tid = threadIdx.x;
  if (blk < 512) {
    const float2* zp = uTp + (size_t)blk * L;
    for (int t = tid; t < L; t += 512) {
      float2 z = zp[t];
      int p = PHY(t);
      sre[p] = z.x; sim[p] = z.y;
    }
  } else {
    const int p2 = blk - 512;
    for (int t = tid; t < L; t += 512) {
      int p = PHY(t);
      sre[p] = eig_vecs[(size_t)t * D + 2 * p2];
      sim[p] = eig_vecs[(size_t)t * D + 2 * p2 + 1];
    }
  }
  for (int t = L + tid; t < NFFT; t += 512) {
    int p = PHY(t);
    sre[p] = 0.f; sim[p] = 0.f;
  }
  __syncthreads();
  dif6(sre, sim, tw, tid);
  // unpack: U_even = (A + conj(Ac))/2 ; U_odd = -i*(A - conj(Ac))/2
  if (blk < 512) {
    float2* r0 = Ubuf + (size_t)(2 * blk) * UST;       // row (b*32 + 2p)
    float2* r1 = r0 + UST;
    for (int f = tid; f <= 2048; f += 512) {
      int pa = PHY(REV4(f));
      int pc = PHY(REV4((NFFT - f) & (NFFT - 1)));
      float Ax = sre[pa], Ay = sim[pa];
      float Bx = sre[pc], By = -sim[pc];
      r0[f] = make_float2(0.5f * (Ax + Bx), 0.5f * (Ay + By));
      float Dx = Ax - Bx, Dy = Ay - By;
      r1[f] = make_float2(0.5f * Dy, -0.5f * Dx);
    }
  } else {
    const int p2 = blk - 512;
    const float sc0 = powf(eig_vals[2 * p2], 0.25f);
    const float sc1 = powf(eig_vals[2 * p2 + 1], 0.25f);
    float2* r0 = Vf + (size_t)(2 * p2) * UST;
    float2* r1 = r0 + UST;
    for (int f = tid; f <= 2048; f += 512) {
      int pa = PHY(REV4(f));
      int pc = PHY(REV4((NFFT - f) & (NFFT - 1)));
      float Ax = sre[pa], Ay = sim[pa];
      float Bx = sre[pc], By = -sim[pc];
      r0[f] = make_float2(0.5f * sc0 * (Ax + Bx), 0.5f * sc0 * (Ay + By));
      float Dx = Ax - Bx, Dy = Ay - By;
      r1[f] = make_float2(0.5f * sc1 * Dy, -0.5f * sc1 * Dx);
    }
  }
}

// ---------------------------------------------------------------- mix v3
// Q[b,o,f] = sum_d Ubuf[b,d,f] * W[f,d,o], W computed on the fly:
//   W[f,d,o] = sum_k Vf[k][f] * m_phi[(k*D+d)*D+o]
// Block: 256 threads = 32 o x 8 fi, FT=8 freqs. W in registers; U staged
// per 8-batch chunk (broadcast reads); output staged via swizzled LDS tile.
#define FT 8
#define BC 8
__global__ __launch_bounds__(256) void k_mix(const float2* __restrict__ Ubuf,
                                             const float2* __restrict__ Vf,
                                             const float* __restrict__ m_phi,
                                             float2* __restrict__ Qbuf) {
  __shared__ float2 Ul[BC][D][FT];
  __shared__ float2 Qs[BC][D][FT];
  __shared__ float2 Vl[D][FT];
  const int f0 = blockIdx.x * FT;
  const int tid = threadIdx.x;
  const int o = tid & 31, fi = tid >> 5;
  const int f = f0 + fi;
  // stage Vl[k][ff] = Vf[k][f0+ff]
  {
    int k = tid >> 3, ff = tid & 7;
    int fff = f0 + ff;
    Vl[k][ff] = (fff < NH) ? Vf[(size_t)k * UST + fff] : make_float2(0.f, 0.f);
  }
  __syncthreads();
  // W fragment: Wr[d] = sum_k Vl[k][fi] * m_phi[(k*D+d)*D+o]
  // (fi-groups of a wave read identical m_phi addresses -> broadcast)
  float2 Wr[D];
  #pragma unroll
  for (int d = 0; d < D; ++d) Wr[d] = make_float2(0.f, 0.f);
  const float* mp = m_phi + o;
  for (int k = 0; k < D; ++k) {
    float2 v = Vl[k][fi];
    const float* mk = mp + (size_t)k * D * D;
    #pragma unroll
    for (int d = 0; d < D; ++d) {
      float m = mk[d * D];
      Wr[d].x += v.x * m;
      Wr[d].y += v.y * m;
    }
  }
  const int lf = tid & 7, row = tid >> 3;      // load/store roles
  for (int b0 = 0; b0 < B; b0 += BC) {
    __syncthreads();
    // stage U chunk: rows (b0+bc)*32+d, cols f0..f0+7 (64B per 8-lane group)
    #pragma unroll
    for (int it = 0; it < 8; ++it) {
      int r = row + it * 32;                   // 0..255
      int bc = r >> 5, d = r & 31;
      int ff = f0 + lf;
      Ul[bc][d][lf] = (ff < NH)
          ? Ubuf[((size_t)(b0 + bc) * D + d) * UST + ff]
          : make_float2(0.f, 0.f);
    }
    __syncthreads();
    // compute: thread (fi,o) does Q[b0+bc][o][f] = sum_d Ul[bc][d][fi]*Wr[d]
    #pragma unroll
    for (int bc = 0; bc < BC; ++bc) {
      float ax = 0.f, ay = 0.f;
      #pragma unroll
      for (int d = 0; d < D; ++d) {
        float2 uu = Ul[bc][d][fi];
        float2 ww = Wr[d];
        ax += uu.x * ww.x - uu.y * ww.y;
        ay += uu.x * ww.y + uu.y * ww.x;
      }
      Qs[bc][o][(fi + o) & 7] = make_float2(ax, ay);   // swizzled store
    }
    __syncthreads();
    // write out coalesced: row (b0+bc)*32+oo, cols f0..f0+7
    #pragma unroll
    for (int it = 0; it < 8; ++it) {
      int r = row + it * 32;
      int bc = r >> 5, oo = r & 31;
      int ff = f0 + lf;
      if (ff < NH)
        Qbuf[((size_t)(b0 + bc) * D + oo) * UST + ff] = Qs[bc][oo][(lf + oo) & 7];
    }
  }
}

// ---------------------------------------------------------------- inverse FFT
// block (b*16+q): packed ifft of Y = Q[2q] + i*Q[2q+1]; Hermitian-extend +
// digit-reverse fused into the load. Output dT rows (b*32+2q), (b*32+2q+1).
__global__ __launch_bounds__(512) void k_ifft(const float2* __restrict__ Qbuf,
                                              const float2* __restrict__ tw,
                                              float* __restrict__ dT) {
  __shared__ float sre[4224];
  __shared__ float sim[4224];
  const int blk = blockIdx.x;          // b*16 + q
  const int tid = threadIdx.x;
  const float2* r0 = Qbuf + (size_t)(2 * blk) * UST;
  const float2* r1 = r0 + UST;
  for (int f = tid; f <= 2048; f += 512) {
    float2 q1 = r0[f], q2 = r1[f];
    int pa = PHY(REV4(f));
    int pc = PHY(REV4((NFFT - f) & (NFFT - 1)));
    // Y[f] = q1 + i*q2 ; Y[N-f] = conj(q1) + i*conj(q2)
    sre[pa] = q1.x - q2.y; sim[pa] = q1.y + q2.x;
    sre[pc] = q1.x + q2.y; sim[pc] = -q1.y + q2.x;
  }
  __syncthreads();
  dit6(sre, sim, tw, tid);
  float* d0 = dT + (size_t)(2 * blk) * L;
  float* d1 = d0 + L;
  const float inv = 1.0f / (float)NFFT;
  for (int t = tid; t < L; t += 512) {
    int p = PHY(t);
    d0[t] = sre[p] * inv;
    d1[t] = sim[p] * inv;
  }
}

// ---------------------------------------------------------------- AR term
// delta[b,t,o] = dT[b,o,t] + sum_{k<=min(t,2)} sum_i m_u[o,i,k]*u[b,t-k,i]
#define TT 64
__global__ __launch_bounds__(256) void k_ar(const float* __restrict__ dT,
                                            const float* __restrict__ u,
                                            const float* __restrict__ m_u,
                                            float* __restrict__ delta) {
  __shared__ float Ds[D][TT + 1];
  __shared__ float Us[TT + 2][D];
  __shared__ float Mt[KU][D][D];      // [k][i][o]
  const int b = blockIdx.y;
  const int t0 = blockIdx.x * TT;
  const int tid = threadIdx.x;
  for (int idx = tid; idx < D * D * KU; idx += blockDim.x) {
    int k = idx % KU, i = (idx / KU) % D, o = idx / (KU * D);
    Mt[k][i][o] = m_u[idx];
  }
  for (int idx = tid; idx < D * TT; idx += blockDim.x) {
    int o = idx >> 6, tt = idx & 63;
    Ds[o][tt] = dT[((size_t)b * D + o) * L + t0 + tt];
  }
  for (int idx = tid; idx < (TT + 2) * D; idx += blockDim.x) {
    int j = idx >> 5, i = idx & 31;
    int t = t0 - 2 + j;
    Us[j][i] = (t >= 0) ? u[((size_t)b * L + t) * D + i] : 0.f;
  }
  __syncthreads();
  const int o = tid & 31, ts = tid >> 5;
  for (int tt = ts; tt < TT; tt += 8) {
    int t = t0 + tt;
    float acc = Ds[o][tt];
    #pragma unroll
    for (int k2 = 0; k2 < KU; ++k2) {
      if (t >= k2) {
        const float* ur = Us[tt + 2 - k2];
        #pragma unroll
        for (int i = 0; i < D; ++i) acc += Mt[k2][i][o] * ur[i];
      }
    }
    delta[((size_t)b * L + t) * D + o] = acc;
  }
}

// ---------------------------------------------------------------- recurrence
// Tc = T^64 where T = [[M0, M1], [I, 0]] (6 squarings)
__global__ __launch_bounds__(1024) void k_tc(const float* __restrict__ m_y,
                                             float* __restrict__ Tc) {
  __shared__ float A[64][68];
  __shared__ float Bb[64][68];
  const int tid = threadIdx.x;
  for (int idx = tid; idx < 64 * 64; idx += blockDim.x) {
    int r = idx >> 6, c = idx & 63;
    float v;
    if (r < 32) v = m_y[(r * 2 + (c >> 5)) * D + (c & 31)];
    else        v = (c == r - 32) ? 1.f : 0.f;
    A[r][c] = v;
  }
  __syncthreads();
  const int r = tid >> 4, cg = tid & 15;
  for (int it = 0; it < 6; ++it) {
    float4 acc = make_float4(0.f, 0.f, 0.f, 0.f);
    for (int i = 0; i < 64; ++i) {
      float a = A[r][i];
      float4 v = *(const float4*)&A[i][cg * 4];
      acc.x += a * v.x; acc.y += a * v.y; acc.z += a * v.z; acc.w += a * v.w;
    }
    __syncthreads();
    *(float4*)&Bb[r][cg * 4] = acc;
    __syncthreads();
    *(float4*)&A[r][cg * 4] = *(const float4*)&Bb[r][cg * 4];
    __syncthreads();
  }
  for (int idx = tid; idx < 64 * 64; idx += blockDim.x)
    Tc[idx] = A[idx >> 6][idx & 63];
}

// Phase A: zero-state chunk response; emit shat[b,c] = [y_{C-1}; y_{C-2}]
// v2: delta chunk staged in LDS so the serial chain has no global-load latency.
__global__ void k_scanA(const float* __restrict__ delta,
                        const float* __restrict__ m_y,
                        float* __restrict__ shat) {
  __shared__ float yb[2][D];
  __shared__ float Dl[CCH][D + 1];
  const int b = blockIdx.y, c = blockIdx.x;
  const int lane = threadIdx.x;            // 64 = one wave
  const int o = lane & 31, h = lane >> 5;
  float m0[16], m1[16];
  #pragma unroll
  for (int i = 0; i < 16; ++i) {
    m0[i] = m_y[(o * 2 + 0) * D + h * 16 + i];
    m1[i] = m_y[(o * 2 + 1) * D + h * 16 + i];
  }
  const float* dp = delta + ((size_t)b * L + c * CCH) * D;
  for (int j = lane; j < CCH * D / 4; j += 64) {
    float4 v = ((const float4*)dp)[j];
    int base = j * 4;
    int r = base >> 5, col = base & 31;
    Dl[r][col] = v.x; Dl[r][col + 1] = v.y;
    Dl[r][col + 2] = v.z; Dl[r][col + 3] = v.w;
  }
  if (lane < D) { yb[0][lane] = 0.f; yb[1][lane] = 0.f; }
  __syncthreads();
  float ylast = 0.f, yprev = 0.f;
  for (int r = 0; r < CCH; ++r) {
    const float* y1 = yb[(r + 1) & 1];
    const float* y2 = yb[r & 1];
    float acc = 0.f;
    #pragma unroll
    for (int i = 0; i < 16; ++i)
      acc += m0[i] * y1[h * 16 + i] + m1[i] * y2[h * 16 + i];
    acc += __shfl_xor(acc, 32);
    float y = acc + Dl[r][o];
    __syncthreads();
    if (h == 0) yb[r & 1][o] = y;
    __syncthreads();
    yprev = ylast; ylast = y;
  }
  if (h == 0) {
    float* sp = shat + ((size_t)b * NCH + c) * 64;
    sp[o] = ylast;
    sp[32 + o] = yprev;
  }
}

// Phase B: inter-chunk state scan, record incoming state per chunk.
__global__ void k_scanB(const float* __restrict__ Tc,
                        const float* __restrict__ shat,
                        float* __restrict__ sin_) {
  __shared__ float TcT[64][65];
  __shared__ float sb[64];
  const int b = blockIdx.x;
  const int r = threadIdx.x;               // 64
  for (int idx = r; idx < 64 * 64; idx += 64) {
    int rr = idx >> 6, cc = idx & 63;
    TcT[cc][rr] = Tc[idx];
  }
  sb[r] = 0.f;
  __syncthreads();
  for (int c = 0; c < NCH; ++c) {
    sin_[((size_t)b * NCH + c) * 64 + r] = sb[r];
    float acc = 0.f;
    #pragma unroll 8
    for (int i = 0; i < 64; ++i) acc += TcT[i][r] * sb[i];
    acc += shat[((size_t)b * NCH + c) * 64 + r];
    __syncthreads();
    sb[r] = acc;
    __syncthreads();
  }
}

// Phase C: re-run each chunk with true incoming state, write output.
// v2: delta chunk staged in LDS (same as scanA).
__global__ void k_scanC(const float* __restrict__ delta,
                        const float* __restrict__ m_y,
                        const float* __restrict__ sin_,
                        float* __restrict__ out) {
  __shared__ float yb[2][D];
  __shared__ float Dl[CCH][D + 1];
  const int b = blockIdx.y, c = blockIdx.x;
  const int lane = threadIdx.x;
  const int o = lane & 31, h = lane >> 5;
  float m0[16], m1[16];
  #pragma unroll
  for (int i = 0; i < 16; ++i) {
    m0[i] = m_y[(o * 2 + 0) * D + h * 16 + i];
    m1[i] = m_y[(o * 2 + 1) * D + h * 16 + i];
  }
  const float* dp = delta + ((size_t)b * L + c * CCH) * D;
  for (int j = lane; j < CCH * D / 4; j += 64) {
    float4 v = ((const float4*)dp)[j];
    int base = j * 4;
    int r = base >> 5, col = base & 31;
    Dl[r][col] = v.x; Dl[r][col + 1] = v.y;
    Dl[r][col + 2] = v.z; Dl[r][col + 3] = v.w;
  }
  const float* sp = sin_ + ((size_t)b * NCH + c) * 64;
  if (lane < 32) yb[1][lane] = sp[lane];        // y_{-1}
  else           yb[0][lane - 32] = sp[lane];   // y_{-2}
  __syncthreads();
  float* op = out + ((size_t)b * L + c * CCH) * D;
  for (int r = 0; r < CCH; ++r) {
    const float* y1 = yb[(r + 1) & 1];
    const float* y2 = yb[r & 1];
    float acc = 0.f;
    #pragma unroll
    for (int i = 0; i < 16; ++i)
      acc += m0[i] * y1[h * 16 + i] + m1[i] * y2[h * 16 + i];
    acc += __shfl_xor(acc, 32);
    float y = acc + Dl[r][o];
    __syncthreads();
    if (h == 0) { yb[r & 1][o] = y; op[r * D + o] = y; }
    __syncthreads();
  }
}

// ---------------------------------------------------------------- launch
extern "C" void kernel_launch(void* const* d_in, const int* in_sizes, int n_in,
                              void* d_out, int out_size, void* d_ws, size_t ws_size,
                              hipStream_t stream) {
  const float* u        = (const float*)d_in[0];
  const float* eig_vals = (const float*)d_in[1];
  const float* eig_vecs = (const float*)d_in[2];
  const float* m_u      = (const float*)d_in[3];
  const float* m_phi    = (const float*)d_in[4];
  const float* m_y      = (const float*)d_in[5];
  float* out = (float*)d_out;

  char* ws = (char*)d_ws;
  size_t off = 0;
  auto alloc = [&](size_t bytes) -> void* {
    void* p = ws + off;
    off += bytes;
    off = (off + 255) & ~(size_t)255;
    return p;
  };
  float2* tw   = (float2*)alloc((size_t)NFFT * sizeof(float2));           // 32 KB
  float2* uTp  = (float2*)alloc((size_t)B * 16 * L * sizeof(float2));     // 8.4 MB
  float2* Vf   = (float2*)alloc((size_t)D * UST * sizeof(float2));        // 0.5 MB
  float2* Ubuf = (float2*)alloc((size_t)B * D * UST * sizeof(float2));    // 16.8 MB
  float2* Qbuf = (float2*)alloc((size_t)B * D * UST * sizeof(float2));    // 16.8 MB
  float*  Tc   = (float*)alloc(64 * 64 * sizeof(float));
  float*  shat = (float*)alloc((size_t)B * NCH * 64 * sizeof(float));
  float*  sinb = (float*)alloc((size_t)B * NCH * 64 * sizeof(float));
  // aliases: dT reuses uTp (dead after k_fft_fwd); delta reuses Ubuf (dead after k_mix)
  float* dT    = (float*)uTp;
  float* delta = (float*)Ubuf;

  k_tr     <<<dim3(L / 64 + 2, B), 256, 0, stream>>>(u, uTp, tw);
  k_fft_fwd<<<528, 512, 0, stream>>>(uTp, eig_vecs, eig_vals, tw, Ubuf, Vf);
  k_mix    <<<(NH + FT - 1) / FT, 256, 0, stream>>>(Ubuf, Vf, m_phi, Qbuf);
  k_ifft   <<<B * 16, 512, 0, stream>>>(Qbuf, tw, dT);
  k_ar     <<<dim3(L / TT, B), 256, 0, stream>>>(dT, u, m_u, delta);
  k_tc     <<<1, 1024, 0, stream>>>(m_y, Tc);
  k_scanA  <<<dim3(NCH, B), 64, 0, stream>>>(delta, m_y, shat);
  k_scanB  <<<B, 64, 0, stream>>>(Tc, shat, sinb);
  k_scanC  <<<dim3(NCH, B), 64, 0, stream>>>(delta, m_y, sinb, out);
}